// Round 2
// baseline (195.180 us; speedup 1.0000x reference)
//
#include <hip/hip_runtime.h>

#define D 256           // embedding dim
#define D4 (D/4)        // float4 chunks per row == 64

__device__ inline float dot4(const float4 u, const float4 v) {
    return u.x*v.x + u.y*v.y + u.z*v.z + u.w*v.w;
}

// full 64-lane butterfly sum (precompute kernel only)
__device__ inline float wsum(float v) {
    #pragma unroll
    for (int off = 32; off > 0; off >>= 1)
        v += __shfl_xor(v, off, 64);
    return v;
}

// One wave per relation r: store r_e row and the 2x2 solve parameters.
// par[r*8] = {m00, m01, m11, aa, ab, dd, 0, 0} where M = ATA_inv (or I/aa fallback)
__global__ __launch_bounds__(256) void transint_pre(
    const float* __restrict__ heads,     // [K, D]
    const float* __restrict__ bases,     // [R, 2, D]
    const int*   __restrict__ rel2head,  // [R]
    const float* __restrict__ rel2mult,  // [R]
    float*       __restrict__ re_buf,    // [R, D]
    float*       __restrict__ par_buf,   // [R, 8]
    int R)
{
    const int wave = (blockIdx.x * blockDim.x + threadIdx.x) >> 6;
    const int lane = threadIdx.x & 63;
    if (wave >= R) return;
    const int r = wave;

    const int hd = rel2head[r];
    const float mult = rel2mult[r];
    const float4* hrow = (const float4*)(heads + (size_t)hd * D);
    const float4* arow = (const float4*)(bases + (size_t)r * 2 * D);

    float4 a0 = arow[lane];
    float4 a1 = arow[D4 + lane];
    float4 re = hrow[lane];
    re.x *= mult; re.y *= mult; re.z *= mult; re.w *= mult;
    ((float4*)(re_buf + (size_t)r * D))[lane] = re;

    float aa = wsum(dot4(a0, a0));
    float ab = wsum(dot4(a0, a1));
    float dd = wsum(dot4(a1, a1));

    float det = aa * dd - ab * ab;
    float m00, m01, m11;
    if (det != 0.0f) {
        float inv = 1.0f / det;
        m00 = dd * inv; m01 = -ab * inv; m11 = aa * inv;
    } else {
        float inv = 1.0f / aa;          // reference fallback: ATA_inv = I / a
        m00 = inv; m01 = 0.0f; m11 = inv;
    }
    if (lane == 0) {
        float* p = par_buf + (size_t)r * 8;
        p[0] = m00; p[1] = m01; p[2] = m11;
        p[3] = aa;  p[4] = ab;  p[5] = dd;
        p[6] = 0.0f; p[7] = 0.0f;
    }
}

// 16 lanes per sample, 4 samples per wave. Lane gl owns float4 chunks
// gl, gl+16, gl+32, gl+48 of each D=256 row. Score via
// ||proj||^2 = ssq - 2 p.c + c^T (A A^T) c,  c = M p   (exact for both branches)
__global__ __launch_bounds__(256) void transint_main(
    const int*   __restrict__ pos_h,
    const int*   __restrict__ pos_t,
    const int*   __restrict__ pos_r,
    const int*   __restrict__ neg_h,
    const int*   __restrict__ neg_t,
    const float* __restrict__ ent_emb,   // [E, D]
    const float* __restrict__ bases,     // [R, 2, D]
    const float* __restrict__ re_buf,    // [R, D]
    const float* __restrict__ par_buf,   // [R, 8]
    float*       __restrict__ out,       // [2*B]
    int nB)
{
    const int wave = (blockIdx.x * blockDim.x + threadIdx.x) >> 6;
    const int lane = threadIdx.x & 63;
    const int g    = lane >> 4;          // sample group within wave
    const int gl   = lane & 15;          // lane within group
    const int b    = wave * 4 + g;
    if (b >= nB) return;

    const int r  = pos_r[b];
    const int ph = pos_h[b];
    const int pt = pos_t[b];
    const int nh = neg_h[b];
    const int nt = neg_t[b];

    const float4* e   = (const float4*)ent_emb;
    const float4* a0p = (const float4*)(bases + (size_t)r * 2 * D);
    const float4* a1p = a0p + D4;
    const float4* rep = (const float4*)(re_buf + (size_t)r * D);
    const float4* php = e + (size_t)ph * D4;
    const float4* ptp = e + (size_t)pt * D4;
    const float4* nhp = e + (size_t)nh * D4;
    const float4* ntp = e + (size_t)nt * D4;

    float p0 = 0.f, p1 = 0.f, n0 = 0.f, n1 = 0.f, ssp = 0.f, ssn = 0.f;

    #pragma unroll
    for (int c = 0; c < 4; ++c) {
        const int idx = gl + 16 * c;
        float4 a0 = a0p[idx];
        float4 a1 = a1p[idx];
        float4 re = rep[idx];
        float4 eh = php[idx];
        float4 et = ptp[idx];
        float4 xh = nhp[idx];
        float4 xt = ntp[idx];

        float4 ps, ns;
        ps.x = eh.x + re.x - et.x;  ns.x = xh.x + re.x - xt.x;
        ps.y = eh.y + re.y - et.y;  ns.y = xh.y + re.y - xt.y;
        ps.z = eh.z + re.z - et.z;  ns.z = xh.z + re.z - xt.z;
        ps.w = eh.w + re.w - et.w;  ns.w = xh.w + re.w - xt.w;

        p0  += dot4(a0, ps);
        p1  += dot4(a1, ps);
        n0  += dot4(a0, ns);
        n1  += dot4(a1, ns);
        ssp += dot4(ps, ps);
        ssn += dot4(ns, ns);
    }

    // 4-stage butterfly within the 16-lane group (offsets < 16 stay in-group)
    #pragma unroll
    for (int off = 8; off > 0; off >>= 1) {
        p0  += __shfl_xor(p0,  off, 64);
        p1  += __shfl_xor(p1,  off, 64);
        n0  += __shfl_xor(n0,  off, 64);
        n1  += __shfl_xor(n1,  off, 64);
        ssp += __shfl_xor(ssp, off, 64);
        ssn += __shfl_xor(ssn, off, 64);
    }

    const float* par = par_buf + (size_t)r * 8;
    const float m00 = par[0], m01 = par[1], m11 = par[2];
    const float aa  = par[3], ab  = par[4], dd  = par[5];

    float c0 = m00 * p0 + m01 * p1;
    float c1 = m01 * p0 + m11 * p1;
    float sp = ssp - 2.f * (p0 * c0 + p1 * c1)
             + (aa * c0 * c0 + 2.f * ab * c0 * c1 + dd * c1 * c1);

    float d0 = m00 * n0 + m01 * n1;
    float d1 = m01 * n0 + m11 * n1;
    float sn = ssn - 2.f * (n0 * d0 + n1 * d1)
             + (aa * d0 * d0 + 2.f * ab * d0 * d1 + dd * d1 * d1);

    if (gl == 0) {
        out[b]      = sp;
        out[nB + b] = sn;
    }
}

extern "C" void kernel_launch(void* const* d_in, const int* in_sizes, int n_in,
                              void* d_out, int out_size, void* d_ws, size_t ws_size,
                              hipStream_t stream) {
    const int*   pos_h    = (const int*)  d_in[0];
    const int*   pos_t    = (const int*)  d_in[1];
    const int*   pos_r    = (const int*)  d_in[2];
    const int*   neg_h    = (const int*)  d_in[3];
    const int*   neg_t    = (const int*)  d_in[4];
    // d_in[5] = neg_r (unused by the reference scores)
    const float* ent_emb  = (const float*)d_in[6];
    const float* heads    = (const float*)d_in[7];
    const float* bases    = (const float*)d_in[8];
    const int*   rel2head = (const int*)  d_in[9];
    const float* rel2mult = (const float*)d_in[10];
    float* out = (float*)d_out;

    const int nB = in_sizes[0];               // 65536
    const int R  = in_sizes[9];               // 1000

    float* re_buf  = (float*)d_ws;            // R*D floats (~1 MB)
    float* par_buf = re_buf + (size_t)R * D;  // R*8 floats

    // precompute per-relation r_e rows + 2x2 solve params (1000 waves)
    {
        const int waves_per_block = 4;
        dim3 grid((R + waves_per_block - 1) / waves_per_block);
        transint_pre<<<grid, dim3(256), 0, stream>>>(
            heads, bases, rel2head, rel2mult, re_buf, par_buf, R);
    }

    // main: 4 samples per wave, 16 samples per 256-thread block
    {
        const int samples_per_block = 16;
        dim3 grid((nB + samples_per_block - 1) / samples_per_block);
        transint_main<<<grid, dim3(256), 0, stream>>>(
            pos_h, pos_t, pos_r, neg_h, neg_t,
            ent_emb, bases, re_buf, par_buf, out, nB);
    }
}